// Round 8
// baseline (666.383 us; speedup 1.0000x reference)
//
#include <hip/hip_runtime.h>

#define HW 16384
#define PIf 3.14159265358979323846f
typedef unsigned short ushortt;
typedef unsigned int uint32;
typedef __attribute__((ext_vector_type(8))) short short8;
typedef __attribute__((ext_vector_type(4))) float f32x4;
typedef __attribute__((ext_vector_type(2))) float f32x2;
typedef __attribute__((ext_vector_type(2))) unsigned int uintv2;

// ---------- bf16 raw helpers ----------
__device__ __forceinline__ float bf2f(ushortt b) {
    return __uint_as_float(((unsigned)b) << 16);
}
__device__ __forceinline__ ushortt f2bf(float f) {
    unsigned u = __float_as_uint(f);
    u += 0x7fffu + ((u >> 16) & 1u);   // RNE
    return (ushortt)(u >> 16);
}
__device__ __forceinline__ int brev6(int v) { return (int)(__brev((unsigned)v) >> 26); }

// ---------- butterfly: (A,B) -> (A+B, (A-B)*t) ----------
__device__ __forceinline__ void bfly(float& Ar, float& Ai, float& Br, float& Bi,
                                     float tr, float ti) {
    float sr = Ar + Br, si = Ai + Bi;
    float dr = Ar - Br, di = Ai - Bi;
    Ar = sr; Ai = si;
    Br = dr * tr - di * ti;
    Bi = dr * ti + di * tr;
}

// ---------- cross-lane re-pairing swaps ----------
__device__ __forceinline__ void xswap32(float& a, float& b) {
    uintv2 r = __builtin_amdgcn_permlane32_swap(__float_as_uint(a), __float_as_uint(b), false, false);
    a = __uint_as_float(r.x); b = __uint_as_float(r.y);
}
__device__ __forceinline__ void xswap16(float& a, float& b) {
    uintv2 r = __builtin_amdgcn_permlane16_swap(__float_as_uint(a), __float_as_uint(b), false, false);
    a = __uint_as_float(r.x); b = __uint_as_float(r.y);
}
template<int IMM>
__device__ __forceinline__ void pswap_sw(float& a, float& b, bool up) {
    float sel = up ? a : b;
    float rcv = __int_as_float(__builtin_amdgcn_ds_swizzle(__float_as_int(sel), IMM));
    a = up ? rcv : a;
    b = up ? b : rcv;
}
template<int CTRL>
__device__ __forceinline__ void pswap_dpp(float& a, float& b, bool up) {
    float sel = up ? a : b;
    float rcv = __int_as_float(__builtin_amdgcn_update_dpp(0, __float_as_int(sel), CTRL, 0xF, 0xF, true));
    a = up ? rcv : a;
    b = up ? b : rcv;
}

struct TwSet { float r0,i0,r1,i1,r2,i2,r3,i3,r4,i4,r5,i5; };

__device__ __forceinline__ TwSet load_tw(const float* __restrict__ twr,
                                         const float* __restrict__ twi, int l) {
    TwSet t;
    t.r0 = twr[l];            t.i0 = twi[l];
    t.r1 = twr[(l & 31) << 1]; t.i1 = twi[(l & 31) << 1];
    t.r2 = twr[(l & 15) << 2]; t.i2 = twi[(l & 15) << 2];
    t.r3 = twr[(l & 7)  << 3]; t.i3 = twi[(l & 7)  << 3];
    t.r4 = twr[(l & 3)  << 4]; t.i4 = twi[(l & 3)  << 4];
    t.r5 = twr[(l & 1)  << 5]; t.i5 = twi[(l & 1)  << 5];
    return t;
}

// ---------- pair-swap 128-pt DIF FFT, 2 complex/lane ----------
// In: lane l holds A=z[l], B=z[l+64]. Out: A=Z[brev6(l)], B=Z[brev6(l)+64].
__device__ __forceinline__ void fft128_ps(float& Ar, float& Ai, float& Br, float& Bi,
                                          const TwSet& t,
                                          bool u8, bool u4, bool u2, bool u1) {
    bfly(Ar, Ai, Br, Bi, t.r0, t.i0);                       // d=64 (in-register)
    xswap32(Ar, Br); xswap32(Ai, Bi);
    bfly(Ar, Ai, Br, Bi, t.r1, t.i1);                       // d=32 (VALU permlane)
    xswap16(Ar, Br); xswap16(Ai, Bi);
    bfly(Ar, Ai, Br, Bi, t.r2, t.i2);                       // d=16 (VALU permlane)
    pswap_sw<0x201F>(Ar, Br, u8); pswap_sw<0x201F>(Ai, Bi, u8);
    bfly(Ar, Ai, Br, Bi, t.r3, t.i3);                       // d=8  (ds_swizzle)
    pswap_sw<0x101F>(Ar, Br, u4); pswap_sw<0x101F>(Ai, Bi, u4);
    bfly(Ar, Ai, Br, Bi, t.r4, t.i4);                       // d=4  (ds_swizzle)
    pswap_dpp<0x4E>(Ar, Br, u2); pswap_dpp<0x4E>(Ai, Bi, u2);
    bfly(Ar, Ai, Br, Bi, t.r5, t.i5);                       // d=2  (DPP)
    pswap_dpp<0xB1>(Ar, Br, u1); pswap_dpp<0xB1>(Ai, Bi, u1);
    {   // d=1, tw = 1
        float sr = Ar + Br, si = Ai + Bi;
        float dr = Ar - Br, di = Ai - Bi;
        Ar = sr; Ai = si; Br = dr; Bi = di;
    }
}

// ---------- Stage A: forward FFT (real-packed) — 66KB LDS, 2 blocks/CU ----------
// Row pass produces only the 64 Z-rows (Hermitian symmetry). Col pass unpacks,
// FFTs, packs output to bf16 (re|im<<16) pairs in registers, and writes IN-PLACE
// into the same 64-row buffer (128 rows x 4B == 64 rows x 8B). Central-7x7 mag
// is accumulated from fp32 registers during the col pass (no precision change).
__global__ __launch_bounds__(1024, 8) void fft_fwd(const float* __restrict__ x,
                                                   ushortt* __restrict__ xfRe,
                                                   ushortt* __restrict__ xfIm,
                                                   float* __restrict__ magc) {
    __shared__ float2 sc[64][129];       // 66048 B; reused as uint32 [64][258]
    __shared__ float twr[64], twi[64];
    int img = blockIdx.x;
    int tid = threadIdx.x, l = tid & 63, wv = tid >> 6;
    if (tid < 64) {
        float s, c;
        sincosf(-PIf * (float)tid / 64.0f, &s, &c);
        twr[tid] = c; twi[tid] = s;
    }
    const float* xi = x + (size_t)img * HW;
    __syncthreads();

    TwSet t = load_tw(twr, twi, l);
    bool u8 = (l & 8) != 0, u4 = (l & 4) != 0, u2 = (l & 2) != 0, u1 = (l & 1) != 0;
    int e = brev6(l);

    // ---- row pass: z = row(2p) + i*row(2p+1), loads upfront, 4 pair-FFTs
    float lar[4], lai[4], lbr[4], lbi[4];
    #pragma unroll
    for (int r = 0; r < 4; ++r) {
        int p = wv * 4 + r;
        lar[r] = xi[(2 * p) * 128 + l];
        lai[r] = xi[(2 * p + 1) * 128 + l];
        lbr[r] = xi[(2 * p) * 128 + 64 + l];
        lbi[r] = xi[(2 * p + 1) * 128 + 64 + l];
    }
    #pragma unroll
    for (int r = 0; r < 4; ++r) {
        int p = wv * 4 + r;
        float Ar = lar[r], Ai = lai[r], Br = lbr[r], Bi = lbi[r];
        fft128_ps(Ar, Ai, Br, Bi, t, u8, u4, u2, u1);
        sc[p][e]      = make_float2(Ar, Ai);   // Z_p natural order, rows 0..63
        sc[p][e + 64] = make_float2(Br, Bi);
    }
    __syncthreads();

    // ---- col pass: unpack rows from Z symmetry, FFT, pack bf16 pairs in regs
    uint32 pkA[8], pkB[8];               // 4 colpairs x (rePair,imPair), rows e / e+64
    int pa = l >> 1, pb = 32 + (l >> 1);
    bool odd = (l & 1) != 0;
    const float scl = 1.0f / 256.0f;
    float pAr = 0.f, pAi = 0.f, pBr = 0.f, pBi = 0.f;
    #pragma unroll
    for (int r = 0; r < 8; ++r) {
        int c = wv * 8 + r, cm = (128 - c) & 127;
        float2 Za = sc[pa][c], Zma = sc[pa][cm];
        float2 Zb = sc[pb][c], Zmb = sc[pb][cm];
        float Ar = odd ? (Za.y + Zma.y) : (Za.x + Zma.x);
        float Ai = odd ? (Zma.x - Za.x) : (Za.y - Zma.y);
        float Br = odd ? (Zb.y + Zmb.y) : (Zb.x + Zmb.x);
        float Bi = odd ? (Zmb.x - Zb.x) : (Zb.y - Zmb.y);
        fft128_ps(Ar, Ai, Br, Bi, t, u8, u4, u2, u1);
        // central 7x7 |xf| from fp32 registers (only waves 0 and 15 can qualify)
        if (wv == 0 || wv == 15) {
            int j7 = (c + 3) & 127;
            if (j7 < 7) {
                int i7a = (e + 3) & 127;
                if (i7a < 7)
                    atomicAdd(&magc[(img >> 8) * 49 + i7a * 7 + j7],
                              sqrtf(Ar * Ar + Ai * Ai) * scl);
                int i7b = (e + 67) & 127;
                if (i7b < 7)
                    atomicAdd(&magc[(img >> 8) * 49 + i7b * 7 + j7],
                              sqrtf(Br * Br + Bi * Bi) * scl);
            }
        }
        if (r & 1) {
            int m = r >> 1;
            pkA[2 * m]     = (uint32)f2bf(pAr * scl) | ((uint32)f2bf(Ar * scl) << 16);
            pkA[2 * m + 1] = (uint32)f2bf(pAi * scl) | ((uint32)f2bf(Ai * scl) << 16);
            pkB[2 * m]     = (uint32)f2bf(pBr * scl) | ((uint32)f2bf(Br * scl) << 16);
            pkB[2 * m + 1] = (uint32)f2bf(pBi * scl) | ((uint32)f2bf(Bi * scl) << 16);
        } else {
            pAr = Ar; pAi = Ai; pBr = Br; pBi = Bi;
        }
    }
    __syncthreads();

    // ---- in-place packed write: uint2 (rePair,imPair) per (row, colpair)
    // row r, colpair m lives at uint32 offset (r>>1)*258 + 4m + 2*(r&1)
    uint32* U = (uint32*)sc;
    int m0 = wv * 4;
    int rowoffA = (e >> 1) * 258 + 2 * (e & 1);
    #pragma unroll
    for (int m = 0; m < 4; ++m) {
        *(uint2*)&U[rowoffA + 4 * (m0 + m)]        = make_uint2(pkA[2 * m], pkA[2 * m + 1]);
        *(uint2*)&U[rowoffA + 32 * 258 + 4 * (m0 + m)] = make_uint2(pkB[2 * m], pkB[2 * m + 1]);
    }
    __syncthreads();

    // ---- coalesced fftshift'd global write
    uint32* oRe = (uint32*)(xfRe + ((size_t)img << 14));
    uint32* oIm = (uint32*)(xfIm + ((size_t)img << 14));
    for (int idx2 = tid; idx2 < 8192; idx2 += 1024) {
        int p = idx2 >> 6, qp = idx2 & 63;
        int u = (p + 64) & 127;
        int m = (qp + 32) & 63;          // colpair after fftshift
        uint2 v = *(const uint2*)&U[(u >> 1) * 258 + 4 * m + 2 * (u & 1)];
        oRe[p * 64 + qp] = v.x;
        oIm[p * 64 + qp] = v.y;
    }
}

// ---------- Stage B: tiny MLP + anisotropic kernel build (pre-paired taps) ----------
__global__ __launch_bounds__(256) void mlp_kern(const float* __restrict__ magc,
                                                const float* __restrict__ w1,
                                                const float* __restrict__ b1,
                                                const float* __restrict__ w2,
                                                const float* __restrict__ b2,
                                                float2* __restrict__ kern_pk) {
    __shared__ float hid[8][32];
    __shared__ float par[8][3];
    __shared__ float kun[8][49];
    __shared__ float ksum[8];
    int tid = threadIdx.x;
    {
        int b = tid >> 5, n = tid & 31;
        float acc = b1[n];
        for (int i = 0; i < 49; ++i)
            acc = fmaf(magc[b * 49 + i] * (1.0f / 256.0f), w1[i * 32 + n], acc);
        hid[b][n] = fmaxf(acc, 0.f);
    }
    __syncthreads();
    if (tid < 24) {
        int b = tid / 3, j = tid % 3;
        float acc = b2[j];
        for (int n = 0; n < 32; ++n) acc = fmaf(hid[b][n], w2[n * 3 + j], acc);
        par[b][j] = acc;
    }
    __syncthreads();
    for (int idx = tid; idx < 392; idx += 256) {
        int b = idx / 49, ij = idx % 49;
        int i = ij / 7, j2 = ij % 7;
        float p0 = par[b][0], p1 = par[b][1], p2 = par[b][2];
        float theta = atan2f(p0, p1) * 0.5f + PIf * 0.5f;
        float lam1 = expf(p2);
        float lam2 = 1.0f / (lam1 + 1e-8f);
        float yy = (float)(i - 3), xx = (float)(j2 - 3);
        float ct, st;
        sincosf(theta, &st, &ct);
        float xr =  xx * ct + yy * st;
        float yr = -xx * st + yy * ct;
        kun[b][ij] = expf(-(xr * xr / (2.f * lam1 * lam1) + yr * yr / (2.f * lam2 * lam2)));
    }
    __syncthreads();
    if (tid < 8) {
        float s = 0.f;
        for (int t = 0; t < 49; ++t) s += kun[tid][t];
        ksum[tid] = s + 1e-8f;
    }
    __syncthreads();
    for (int idx = tid; idx < 448; idx += 256) {
        int b  = idx / 56;
        int r7 = idx - b * 56;
        int rr = r7 / 7, dx = r7 - rr * 7;
        float inv = 1.0f / ksum[b];
        float v0 = (rr < 7)  ? kun[b][rr * 7 + dx] * inv       : 0.f;
        float v1 = (rr >= 1) ? kun[b][(rr - 1) * 7 + dx] * inv : 0.f;
        kern_pk[idx] = make_float2(v0, v1);
    }
}

// ---------- Stage C: channel mixing via bf16 MFMA, direct [c][pix] input ----------
__global__ __launch_bounds__(256) void gemm_mix(const ushortt* __restrict__ xfRe,
                                                const ushortt* __restrict__ xfIm,
                                                const float* __restrict__ wr,
                                                ushortt* __restrict__ mixRe,
                                                ushortt* __restrict__ mixIm) {
    __shared__ ushortt lA[2][5120];   // [o=128][k=32] stride 40 ushorts
    __shared__ uint32  lB[2][2560];   // [pix=128][k2=16(+4 pad)] dwords, swizzled
    int tid = threadIdx.x;
    int lane = tid & 63, wave = tid >> 6;
    int wm = wave >> 1, wn = wave & 1;
    int l15 = lane & 15, q4 = lane >> 4;
    int b = blockIdx.z >> 1, part = blockIdx.z & 1;
    const ushortt* Xb = (part ? xfIm : xfRe) + (size_t)b * (256 * HW)
                        + blockIdx.x * 128;
    ushortt* Dst = (part ? mixIm : mixRe) + (size_t)b * (256 * HW)
                   + (size_t)(blockIdx.y * 128) * HW + blockIdx.x * 128;
    const float* W = wr + (blockIdx.y * 128) * 256;

    int srow = tid >> 1, shalf = tid & 1;
    const float* wRow = W + srow * 256 + shalf * 16;
    int ldsOffA = srow * 40 + shalf * 16;

    int kt = tid >> 4;                 // 0..15
    int pq = tid & 15;                 // 0..15
    int kswz = kt ^ ((pq & 3) << 2);   // octet-bit XOR swizzle
    int rowbase = pq * 160;            // pq*8 rows * 20 dwords

    float4 wreg[4];
    uint4  a0, a1;
    #pragma unroll
    for (int i = 0; i < 4; ++i) wreg[i] = *(const float4*)(wRow + i * 4);
    {
        const ushortt* xp = Xb + (size_t)(2 * kt) * HW + pq * 8;
        a0 = *(const uint4*)xp;
        a1 = *(const uint4*)(xp + HW);
    }

    f32x4 acc[4][4];
    #pragma unroll
    for (int i = 0; i < 4; ++i)
        #pragma unroll
        for (int j = 0; j < 4; ++j)
            #pragma unroll
            for (int k = 0; k < 4; ++k) acc[i][j][k] = 0.f;

    int abase = (wm * 64 + l15) * 40 + q4 * 8;
    int baddr[4];
    #pragma unroll
    for (int f = 0; f < 4; ++f) {
        int pf = wn * 64 + f * 16 + l15;
        baddr[f] = pf * 40 + ((q4 ^ ((pf >> 3) & 3)) << 3);
    }

    for (int kb = 0; kb < 8; ++kb) {
        int bufc = kb & 1;
        {
            float ff[16] = {wreg[0].x, wreg[0].y, wreg[0].z, wreg[0].w,
                            wreg[1].x, wreg[1].y, wreg[1].z, wreg[1].w,
                            wreg[2].x, wreg[2].y, wreg[2].z, wreg[2].w,
                            wreg[3].x, wreg[3].y, wreg[3].z, wreg[3].w};
            uint32 p[8];
            #pragma unroll
            for (int j = 0; j < 8; ++j)
                p[j] = (uint32)f2bf(ff[2 * j]) | ((uint32)f2bf(ff[2 * j + 1]) << 16);
            *(uint4*)&lA[bufc][ldsOffA]     = make_uint4(p[0], p[1], p[2], p[3]);
            *(uint4*)&lA[bufc][ldsOffA + 8] = make_uint4(p[4], p[5], p[6], p[7]);
        }
        {
            uint32 d[8];
            d[0] = (a0.x & 0xffffu) | (a1.x << 16);
            d[1] = (a0.x >> 16)     | (a1.x & 0xffff0000u);
            d[2] = (a0.y & 0xffffu) | (a1.y << 16);
            d[3] = (a0.y >> 16)     | (a1.y & 0xffff0000u);
            d[4] = (a0.z & 0xffffu) | (a1.z << 16);
            d[5] = (a0.z >> 16)     | (a1.z & 0xffff0000u);
            d[6] = (a0.w & 0xffffu) | (a1.w << 16);
            d[7] = (a0.w >> 16)     | (a1.w & 0xffff0000u);
            uint32* lb = lB[bufc];
            #pragma unroll
            for (int j = 0; j < 8; ++j) lb[rowbase + j * 20 + kswz] = d[j];
        }
        __syncthreads();
        if (kb < 7) {
            const float* wN = wRow + (kb + 1) * 32;
            #pragma unroll
            for (int i = 0; i < 4; ++i) wreg[i] = *(const float4*)(wN + i * 4);
            const ushortt* xp = Xb + (size_t)((kb + 1) * 32 + 2 * kt) * HW + pq * 8;
            a0 = *(const uint4*)xp;
            a1 = *(const uint4*)(xp + HW);
        }
        short8 af[4], bf[4];
        const ushortt* lbU = (const ushortt*)lB[bufc];
        #pragma unroll
        for (int f = 0; f < 4; ++f) af[f] = *(const short8*)&lA[bufc][abase + f * 640];
        #pragma unroll
        for (int f = 0; f < 4; ++f) bf[f] = *(const short8*)&lbU[baddr[f]];
        #pragma unroll
        for (int fi = 0; fi < 4; ++fi)
            #pragma unroll
            for (int fj = 0; fj < 4; ++fj)
                acc[fi][fj] = __builtin_amdgcn_mfma_f32_16x16x32_bf16(
                    af[fi], bf[fj], acc[fi][fj], 0, 0, 0);
    }
    #pragma unroll
    for (int fi = 0; fi < 4; ++fi) {
        #pragma unroll
        for (int r = 0; r < 4; ++r) {
            int o_l = wm * 64 + fi * 16 + q4 * 4 + r;
            ushortt* dp = Dst + (size_t)o_l * HW + wn * 64 + l15;
            #pragma unroll
            for (int fj = 0; fj < 4; ++fj)
                dp[fj * 16] = f2bf(acc[fi][fj][r]);
        }
    }
}

// ---------- Stage D: 7x7 zero-padded conv, packed-fp32 dual-row FMA ----------
__global__ __launch_bounds__(256) void conv7(const ushortt* __restrict__ mixRe,
                                             const ushortt* __restrict__ mixIm,
                                             const float2* __restrict__ kern_pk,
                                             ushortt* __restrict__ outRe,
                                             ushortt* __restrict__ outIm) {
    __shared__ float tile[70 * 73];
    int b = blockIdx.z;
    int plane = blockIdx.y;
    int part = plane >> 8;
    size_t pbase = ((size_t)(b * 256 + (plane & 255))) << 14;
    const ushortt* src = (part ? mixIm : mixRe) + pbase;
    ushortt* dst = (part ? outIm : outRe) + pbase;
    int ty = (blockIdx.x >> 1) * 64, tx = (blockIdx.x & 1) * 64;
    int tid = threadIdx.x;
    const float2* kp = kern_pk + b * 56;

    for (int idx = tid; idx < 2520; idx += 256) {
        int row = idx / 36, du = idx - row * 36;
        int gy = ty + row - 3, gx0 = tx - 4 + 2 * du;
        uint32 v = 0u;
        if ((unsigned)gy < 128u && (unsigned)gx0 < 128u)
            v = *(const uint32*)(src + gy * 128 + gx0);
        int base = row * 73 + 2 * du;
        tile[base]     = __uint_as_float(v << 16);
        tile[base + 1] = __uint_as_float(v & 0xffff0000u);
    }
    __syncthreads();

    int ox = (tid & 7) * 8, oy = (tid >> 3) * 2;
    f32x2 acc2[8];
    #pragma unroll
    for (int j = 0; j < 8; ++j) { acc2[j].x = 0.f; acc2[j].y = 0.f; }

    #pragma unroll
    for (int dyy = 0; dyy < 8; ++dyy) {
        float row[14];
        #pragma unroll
        for (int m = 0; m < 14; ++m) row[m] = tile[(oy + dyy) * 73 + ox + 1 + m];
        #pragma unroll
        for (int dx = 0; dx < 7; ++dx) {
            float2 kl = kp[dyy * 7 + dx];
            f32x2 kk; kk.x = kl.x; kk.y = kl.y;
            #pragma unroll
            for (int j = 0; j < 8; ++j) {
                f32x2 rr; rr.x = row[dx + j]; rr.y = row[dx + j];
                acc2[j] = __builtin_elementwise_fma(rr, kk, acc2[j]);
            }
        }
    }

    uint32 s0[4], s1[4];
    #pragma unroll
    for (int m = 0; m < 4; ++m) {
        s0[m] = (uint32)f2bf(acc2[2 * m].x) | ((uint32)f2bf(acc2[2 * m + 1].x) << 16);
        s1[m] = (uint32)f2bf(acc2[2 * m].y) | ((uint32)f2bf(acc2[2 * m + 1].y) << 16);
    }
    *(uint4*)(dst + (ty + oy) * 128 + tx + ox)     = make_uint4(s0[0], s0[1], s0[2], s0[3]);
    *(uint4*)(dst + (ty + oy + 1) * 128 + tx + ox) = make_uint4(s1[0], s1[1], s1[2], s1[3]);
}

// ---------- Stage E: ifftshift + IFFT (conj trick, paired real-output cols) + x ----------
__global__ __launch_bounds__(1024) void ifft_add(const ushortt* __restrict__ convRe,
                                                 const ushortt* __restrict__ convIm,
                                                 const float* __restrict__ x,
                                                 float* __restrict__ out) {
    __shared__ float2 sc[128][129];
    __shared__ float twr[64], twi[64];
    int img = blockIdx.x;
    int tid = threadIdx.x, l = tid & 63, wv = tid >> 6;
    if (tid < 64) {
        float s, c;
        sincosf(-PIf * (float)tid / 64.0f, &s, &c);
        twr[tid] = c; twi[tid] = s;
    }
    const ushortt* cr = convRe + ((size_t)img << 14);
    const ushortt* ci = convIm + ((size_t)img << 14);
    __syncthreads();

    TwSet t = load_tw(twr, twi, l);
    bool u8 = (l & 8) != 0, u4 = (l & 4) != 0, u2 = (l & 2) != 0, u1 = (l & 1) != 0;
    int e = brev6(l);

    // ---- row pass: ifftshift gather (conj), ALL loads upfront, 8 FFTs
    {
        float nar[8], nai[8], nbr[8], nbi[8];
        #pragma unroll
        for (int r = 0; r < 8; ++r) {
            int p = ((wv * 8 + r) + 64) & 127;
            nar[r] = bf2f(cr[p * 128 + 64 + l]);
            nai[r] = bf2f(ci[p * 128 + 64 + l]);
            nbr[r] = bf2f(cr[p * 128 + l]);
            nbi[r] = bf2f(ci[p * 128 + l]);
        }
        #pragma unroll
        for (int r = 0; r < 8; ++r) {
            int u = wv * 8 + r;
            float Ar = nar[r], Ai = -nai[r], Br = nbr[r], Bi = -nbi[r];
            fft128_ps(Ar, Ai, Br, Bi, t, u8, u4, u2, u1);
            sc[u][e]      = make_float2(Ar, Ai);
            sc[u][e + 64] = make_float2(Br, Bi);
        }
    }
    __syncthreads();

    // ---- col pass: 4 column-PAIR FFTs per wave, staged in regs
    float oar[4], oai[4], obr[4], obi[4];
    int rv  = (128 - l) & 127;       // reverse of row l
    int rv2 = (64 - l) & 127;        // reverse of row l+64
    #pragma unroll
    for (int r = 0; r < 4; ++r) {
        int m = wv * 4 + r;
        int c0 = 2 * m, c1 = 2 * m + 1;
        float2 P  = sc[l][c0],      R  = sc[l][c1];
        float2 Q  = sc[rv][c0],     S  = sc[rv][c1];
        float2 P2 = sc[l + 64][c0], R2 = sc[l + 64][c1];
        float2 Q2 = sc[rv2][c0],    S2 = sc[rv2][c1];
        float Ar = P.x + Q.x - R.y + S.y;
        float Ai = P.y - Q.y + R.x + S.x;
        float Br = P2.x + Q2.x - R2.y + S2.y;
        float Bi = P2.y - Q2.y + R2.x + S2.x;
        fft128_ps(Ar, Ai, Br, Bi, t, u8, u4, u2, u1);
        oar[r] = Ar; oai[r] = Ai; obr[r] = Br; obi[r] = Bi;
    }
    __syncthreads();
    #pragma unroll
    for (int r = 0; r < 4; ++r) {
        int m = wv * 4 + r;
        sc[e][m]      = make_float2(oar[r], oai[r]);   // (.x=col 2m, .y=col 2m+1)
        sc[e + 64][m] = make_float2(obr[r], obi[r]);
    }
    __syncthreads();

    // ---- output: slot m -> columns (2m, 2m+1); scale 1/256 (conj-trick 1/128 * pack 1/2)
    const float* xi = x + (size_t)img * HW;
    float* oo = out + (size_t)img * HW;
    for (int idx2 = tid; idx2 < 8192; idx2 += 1024) {
        int y = idx2 >> 6, m = idx2 & 63;
        float2 v = sc[y][m];
        float2 xv = *(const float2*)(xi + y * 128 + 2 * m);
        float2 ov;
        ov.x = v.x * (1.0f / 256.0f) + xv.x;
        ov.y = v.y * (1.0f / 256.0f) + xv.y;
        *(float2*)(oo + y * 128 + 2 * m) = ov;
    }
}

extern "C" void kernel_launch(void* const* d_in, const int* in_sizes, int n_in,
                              void* d_out, int out_size, void* d_ws, size_t ws_size,
                              hipStream_t stream) {
    const float* x  = (const float*)d_in[0];
    const float* w1 = (const float*)d_in[1];
    const float* b1 = (const float*)d_in[2];
    const float* w2 = (const float*)d_in[3];
    const float* b2 = (const float*)d_in[4];
    const float* wr = (const float*)d_in[5];

    char* ws = (char*)d_ws;
    ushortt* xfRe  = (ushortt*)ws;                       // 64 MiB
    ushortt* xfIm  = xfRe + 33554432;                    // 64 MiB
    ushortt* mixRe = (ushortt*)(ws + 134217728);         // 64 MiB (separate: gemm in != out)
    ushortt* mixIm = mixRe + 33554432;                   // 64 MiB
    ushortt* convRe = xfRe, *convIm = xfIm;              // aliases (xf dead after gemm)
    float* magc = (float*)(ws + 268435456);
    float2* kern_pk = (float2*)(ws + 268435456 + 2048);  // 448 float2 = 3584 B

    hipMemsetAsync(magc, 0, 392 * sizeof(float), stream);
    fft_fwd<<<2048, 1024, 0, stream>>>(x, xfRe, xfIm, magc);
    mlp_kern<<<1, 256, 0, stream>>>(magc, w1, b1, w2, b2, kern_pk);
    gemm_mix<<<dim3(128, 2, 16), 256, 0, stream>>>(xfRe, xfIm, wr, mixRe, mixIm);
    conv7<<<dim3(4, 512, 8), 256, 0, stream>>>(mixRe, mixIm, kern_pk, convRe, convIm);
    ifft_add<<<2048, 1024, 0, stream>>>(convRe, convIm, x, (float*)d_out);
}

// Round 9
// 562.609 us; speedup vs baseline: 1.1844x; 1.1844x over previous
//
#include <hip/hip_runtime.h>

#define HW 16384
#define PIf 3.14159265358979323846f
typedef unsigned short ushortt;
typedef unsigned int uint32;
typedef __attribute__((ext_vector_type(8))) short short8;
typedef __attribute__((ext_vector_type(4))) float f32x4;
typedef __attribute__((ext_vector_type(2))) float f32x2;
typedef __attribute__((ext_vector_type(2))) unsigned int uintv2;

// ---------- bf16 raw helpers ----------
__device__ __forceinline__ float bf2f(ushortt b) {
    return __uint_as_float(((unsigned)b) << 16);
}
__device__ __forceinline__ ushortt f2bf(float f) {
    unsigned u = __float_as_uint(f);
    u += 0x7fffu + ((u >> 16) & 1u);   // RNE
    return (ushortt)(u >> 16);
}
__device__ __forceinline__ int brev6(int v) { return (int)(__brev((unsigned)v) >> 26); }

// ---------- butterfly: (A,B) -> (A+B, (A-B)*t) ----------
__device__ __forceinline__ void bfly(float& Ar, float& Ai, float& Br, float& Bi,
                                     float tr, float ti) {
    float sr = Ar + Br, si = Ai + Bi;
    float dr = Ar - Br, di = Ai - Bi;
    Ar = sr; Ai = si;
    Br = dr * tr - di * ti;
    Bi = dr * ti + di * tr;
}

// ---------- cross-lane re-pairing swaps ----------
__device__ __forceinline__ void xswap32(float& a, float& b) {
    uintv2 r = __builtin_amdgcn_permlane32_swap(__float_as_uint(a), __float_as_uint(b), false, false);
    a = __uint_as_float(r.x); b = __uint_as_float(r.y);
}
__device__ __forceinline__ void xswap16(float& a, float& b) {
    uintv2 r = __builtin_amdgcn_permlane16_swap(__float_as_uint(a), __float_as_uint(b), false, false);
    a = __uint_as_float(r.x); b = __uint_as_float(r.y);
}
template<int IMM>
__device__ __forceinline__ void pswap_sw(float& a, float& b, bool up) {
    float sel = up ? a : b;
    float rcv = __int_as_float(__builtin_amdgcn_ds_swizzle(__float_as_int(sel), IMM));
    a = up ? rcv : a;
    b = up ? b : rcv;
}
template<int CTRL>
__device__ __forceinline__ void pswap_dpp(float& a, float& b, bool up) {
    float sel = up ? a : b;
    float rcv = __int_as_float(__builtin_amdgcn_update_dpp(0, __float_as_int(sel), CTRL, 0xF, 0xF, true));
    a = up ? rcv : a;
    b = up ? b : rcv;
}

struct TwSet { float r0,i0,r1,i1,r2,i2,r3,i3,r4,i4,r5,i5; };

__device__ __forceinline__ TwSet load_tw(const float* __restrict__ twr,
                                         const float* __restrict__ twi, int l) {
    TwSet t;
    t.r0 = twr[l];            t.i0 = twi[l];
    t.r1 = twr[(l & 31) << 1]; t.i1 = twi[(l & 31) << 1];
    t.r2 = twr[(l & 15) << 2]; t.i2 = twi[(l & 15) << 2];
    t.r3 = twr[(l & 7)  << 3]; t.i3 = twi[(l & 7)  << 3];
    t.r4 = twr[(l & 3)  << 4]; t.i4 = twi[(l & 3)  << 4];
    t.r5 = twr[(l & 1)  << 5]; t.i5 = twi[(l & 1)  << 5];
    return t;
}

// ---------- pair-swap 128-pt DIF FFT, 2 complex/lane ----------
// In: lane l holds A=z[l], B=z[l+64]. Out: A=Z[brev6(l)], B=Z[brev6(l)+64].
__device__ __forceinline__ void fft128_ps(float& Ar, float& Ai, float& Br, float& Bi,
                                          const TwSet& t,
                                          bool u8, bool u4, bool u2, bool u1) {
    bfly(Ar, Ai, Br, Bi, t.r0, t.i0);                       // d=64 (in-register)
    xswap32(Ar, Br); xswap32(Ai, Bi);
    bfly(Ar, Ai, Br, Bi, t.r1, t.i1);                       // d=32 (VALU permlane)
    xswap16(Ar, Br); xswap16(Ai, Bi);
    bfly(Ar, Ai, Br, Bi, t.r2, t.i2);                       // d=16 (VALU permlane)
    pswap_sw<0x201F>(Ar, Br, u8); pswap_sw<0x201F>(Ai, Bi, u8);
    bfly(Ar, Ai, Br, Bi, t.r3, t.i3);                       // d=8  (ds_swizzle)
    pswap_sw<0x101F>(Ar, Br, u4); pswap_sw<0x101F>(Ai, Bi, u4);
    bfly(Ar, Ai, Br, Bi, t.r4, t.i4);                       // d=4  (ds_swizzle)
    pswap_dpp<0x4E>(Ar, Br, u2); pswap_dpp<0x4E>(Ai, Bi, u2);
    bfly(Ar, Ai, Br, Bi, t.r5, t.i5);                       // d=2  (DPP)
    pswap_dpp<0xB1>(Ar, Br, u1); pswap_dpp<0xB1>(Ai, Bi, u1);
    {   // d=1, tw = 1
        float sr = Ar + Br, si = Ai + Bi;
        float dr = Ar - Br, di = Ai - Bi;
        Ar = sr; Ai = si; Br = dr; Bi = di;
    }
}

// ---------- Stage A: forward FFT (real-packed rows) + fftshift + central-mag ----------
// R7 version (132KB LDS, 1 block/CU): R8's 66KB/2-block variant regressed —
// DS-pipe + L3 streaming saturate with 2 resident blocks; occupancy is not the lever.
__global__ __launch_bounds__(1024) void fft_fwd(const float* __restrict__ x,
                                                ushortt* __restrict__ xfRe,
                                                ushortt* __restrict__ xfIm,
                                                float* __restrict__ magc) {
    __shared__ float2 sc[128][129];
    __shared__ float twr[64], twi[64];
    int img = blockIdx.x;
    int tid = threadIdx.x, l = tid & 63, wv = tid >> 6;
    if (tid < 64) {
        float s, c;
        sincosf(-PIf * (float)tid / 64.0f, &s, &c);
        twr[tid] = c; twi[tid] = s;
    }
    const float* xi = x + (size_t)img * HW;
    __syncthreads();

    TwSet t = load_tw(twr, twi, l);
    bool u8 = (l & 8) != 0, u4 = (l & 4) != 0, u2 = (l & 2) != 0, u1 = (l & 1) != 0;
    int e = brev6(l);

    // ---- row pass: z = row(2p) + i*row(2p+1), loads upfront, 4 pair-FFTs
    float lar[4], lai[4], lbr[4], lbi[4];
    #pragma unroll
    for (int r = 0; r < 4; ++r) {
        int p = wv * 4 + r;
        lar[r] = xi[(2 * p) * 128 + l];
        lai[r] = xi[(2 * p + 1) * 128 + l];
        lbr[r] = xi[(2 * p) * 128 + 64 + l];
        lbi[r] = xi[(2 * p + 1) * 128 + 64 + l];
    }
    #pragma unroll
    for (int r = 0; r < 4; ++r) {
        int p = wv * 4 + r;
        float Ar = lar[r], Ai = lai[r], Br = lbr[r], Bi = lbi[r];
        fft128_ps(Ar, Ai, Br, Bi, t, u8, u4, u2, u1);
        sc[p][e]      = make_float2(Ar, Ai);   // Z_p natural order, rows 0..63
        sc[p][e + 64] = make_float2(Br, Bi);
    }
    __syncthreads();

    // ---- col pass: unpack rows from Z symmetry, FFT, stage in regs
    float oar[8], oai[8], obr[8], obi[8];
    int pa = l >> 1, pb = 32 + (l >> 1);
    bool odd = (l & 1) != 0;
    #pragma unroll
    for (int r = 0; r < 8; ++r) {
        int c = wv * 8 + r, cm = (128 - c) & 127;
        float2 Za = sc[pa][c], Zma = sc[pa][cm];
        float2 Zb = sc[pb][c], Zmb = sc[pb][cm];
        float Ar = odd ? (Za.y + Zma.y) : (Za.x + Zma.x);
        float Ai = odd ? (Zma.x - Za.x) : (Za.y - Zma.y);
        float Br = odd ? (Zb.y + Zmb.y) : (Zb.x + Zmb.x);
        float Bi = odd ? (Zmb.x - Zb.x) : (Zb.y - Zmb.y);
        fft128_ps(Ar, Ai, Br, Bi, t, u8, u4, u2, u1);
        oar[r] = Ar; oai[r] = Ai; obr[r] = Br; obi[r] = Bi;
    }
    __syncthreads();
    #pragma unroll
    for (int r = 0; r < 8; ++r) {
        int c = wv * 8 + r;
        sc[e][c]      = make_float2(oar[r], oai[r]);
        sc[e + 64][c] = make_float2(obr[r], obi[r]);
    }
    __syncthreads();

    // coalesced fftshift'd bf16 write (ortho 1/128, plus 1/2 unpack fold -> 1/256)
    uint32* oRe = (uint32*)(xfRe + ((size_t)img << 14));
    uint32* oIm = (uint32*)(xfIm + ((size_t)img << 14));
    for (int idx2 = tid; idx2 < 8192; idx2 += 1024) {
        int p = idx2 >> 6, qp = idx2 & 63, q = qp * 2;
        int u  = (p + 64) & 127;
        int v0 = (q + 64) & 127;          // even, pair contiguous
        const float scl = 1.0f / 256.0f;
        float2 e0 = sc[u][v0], e1 = sc[u][v0 + 1];
        uint32 re = (uint32)f2bf(e0.x * scl) | ((uint32)f2bf(e1.x * scl) << 16);
        uint32 im = (uint32)f2bf(e0.y * scl) | ((uint32)f2bf(e1.y * scl) << 16);
        oRe[p * 64 + qp] = re;
        oIm[p * 64 + qp] = im;
    }
    // central 7x7 |xf| accumulation (fp32)
    if (tid < 49) {
        int p = 61 + tid / 7, q = 61 + tid % 7;
        int u = (p + 64) & 127, v = (q + 64) & 127;
        float2 z = sc[u][v];
        float mag = sqrtf(z.x * z.x + z.y * z.y) * (1.0f / 256.0f);
        atomicAdd(&magc[(img >> 8) * 49 + tid], mag);
    }
}

// ---------- Stage B: tiny MLP + aniso kernels + wr->bf16 pre-conversion ----------
// wbf[o*256+k] = f2bf(wr[o*256+k]) — done ONCE here so gemm_mix doesn't pay
// 16 f2bf packs per thread per k-step (it was gemm's dominant VALU cost).
__global__ __launch_bounds__(256) void mlp_kern(const float* __restrict__ magc,
                                                const float* __restrict__ w1,
                                                const float* __restrict__ b1,
                                                const float* __restrict__ w2,
                                                const float* __restrict__ b2,
                                                const float* __restrict__ wr,
                                                float2* __restrict__ kern_pk,
                                                ushortt* __restrict__ wbf) {
    __shared__ float hid[8][32];
    __shared__ float par[8][3];
    __shared__ float kun[8][49];
    __shared__ float ksum[8];
    int tid = threadIdx.x;
    // ---- wr -> bf16 (65536 elems, vectorized)
    for (int i4 = tid; i4 < 16384; i4 += 256) {
        float4 w = *(const float4*)(wr + i4 * 4);
        uint2 o;
        o.x = (uint32)f2bf(w.x) | ((uint32)f2bf(w.y) << 16);
        o.y = (uint32)f2bf(w.z) | ((uint32)f2bf(w.w) << 16);
        *(uint2*)(wbf + i4 * 4) = o;
    }
    {
        int b = tid >> 5, n = tid & 31;
        float acc = b1[n];
        for (int i = 0; i < 49; ++i)
            acc = fmaf(magc[b * 49 + i] * (1.0f / 256.0f), w1[i * 32 + n], acc);
        hid[b][n] = fmaxf(acc, 0.f);
    }
    __syncthreads();
    if (tid < 24) {
        int b = tid / 3, j = tid % 3;
        float acc = b2[j];
        for (int n = 0; n < 32; ++n) acc = fmaf(hid[b][n], w2[n * 3 + j], acc);
        par[b][j] = acc;
    }
    __syncthreads();
    for (int idx = tid; idx < 392; idx += 256) {
        int b = idx / 49, ij = idx % 49;
        int i = ij / 7, j2 = ij % 7;
        float p0 = par[b][0], p1 = par[b][1], p2 = par[b][2];
        float theta = atan2f(p0, p1) * 0.5f + PIf * 0.5f;
        float lam1 = expf(p2);
        float lam2 = 1.0f / (lam1 + 1e-8f);
        float yy = (float)(i - 3), xx = (float)(j2 - 3);
        float ct, st;
        sincosf(theta, &st, &ct);
        float xr =  xx * ct + yy * st;
        float yr = -xx * st + yy * ct;
        kun[b][ij] = expf(-(xr * xr / (2.f * lam1 * lam1) + yr * yr / (2.f * lam2 * lam2)));
    }
    __syncthreads();
    if (tid < 8) {
        float s = 0.f;
        for (int t = 0; t < 49; ++t) s += kun[tid][t];
        ksum[tid] = s + 1e-8f;
    }
    __syncthreads();
    for (int idx = tid; idx < 448; idx += 256) {
        int b  = idx / 56;
        int r7 = idx - b * 56;
        int rr = r7 / 7, dx = r7 - rr * 7;
        float inv = 1.0f / ksum[b];
        float v0 = (rr < 7)  ? kun[b][rr * 7 + dx] * inv       : 0.f;
        float v1 = (rr >= 1) ? kun[b][(rr - 1) * 7 + dx] * inv : 0.f;
        kern_pk[idx] = make_float2(v0, v1);
    }
}

// ---------- Stage C: channel mixing via bf16 MFMA, direct [c][pix] input ----------
// A-operand now pre-converted bf16 (wbf): staging = two uint4 copies, no f2bf.
__global__ __launch_bounds__(256) void gemm_mix(const ushortt* __restrict__ xfRe,
                                                const ushortt* __restrict__ xfIm,
                                                const ushortt* __restrict__ wbf,
                                                ushortt* __restrict__ mixRe,
                                                ushortt* __restrict__ mixIm) {
    __shared__ ushortt lA[2][5120];   // [o=128][k=32] stride 40 ushorts
    __shared__ uint32  lB[2][2560];   // [pix=128][k2=16(+4 pad)] dwords, swizzled
    int tid = threadIdx.x;
    int lane = tid & 63, wave = tid >> 6;
    int wm = wave >> 1, wn = wave & 1;
    int l15 = lane & 15, q4 = lane >> 4;
    int b = blockIdx.z >> 1, part = blockIdx.z & 1;
    const ushortt* Xb = (part ? xfIm : xfRe) + (size_t)b * (256 * HW)
                        + blockIdx.x * 128;
    ushortt* Dst = (part ? mixIm : mixRe) + (size_t)b * (256 * HW)
                   + (size_t)(blockIdx.y * 128) * HW + blockIdx.x * 128;

    int srow = tid >> 1, shalf = tid & 1;
    const ushortt* wbRow = wbf + (size_t)(blockIdx.y * 128 + srow) * 256 + shalf * 16;
    int ldsOffA = srow * 40 + shalf * 16;

    int kt = tid >> 4;                 // 0..15
    int pq = tid & 15;                 // 0..15
    int kswz = kt ^ ((pq & 3) << 2);   // octet-bit XOR swizzle
    int rowbase = pq * 160;            // pq*8 rows * 20 dwords

    uint4 wu0, wu1;
    uint4 a0, a1;
    wu0 = *(const uint4*)(wbRow);
    wu1 = *(const uint4*)(wbRow + 8);
    {
        const ushortt* xp = Xb + (size_t)(2 * kt) * HW + pq * 8;
        a0 = *(const uint4*)xp;
        a1 = *(const uint4*)(xp + HW);
    }

    f32x4 acc[4][4];
    #pragma unroll
    for (int i = 0; i < 4; ++i)
        #pragma unroll
        for (int j = 0; j < 4; ++j)
            #pragma unroll
            for (int k = 0; k < 4; ++k) acc[i][j][k] = 0.f;

    int abase = (wm * 64 + l15) * 40 + q4 * 8;
    int baddr[4];
    #pragma unroll
    for (int f = 0; f < 4; ++f) {
        int pf = wn * 64 + f * 16 + l15;
        baddr[f] = pf * 40 + ((q4 ^ ((pf >> 3) & 3)) << 3);
    }

    for (int kb = 0; kb < 8; ++kb) {
        int bufc = kb & 1;
        // ---- A: direct bf16 copy to LDS
        *(uint4*)&lA[bufc][ldsOffA]     = wu0;
        *(uint4*)&lA[bufc][ldsOffA + 8] = wu1;
        // ---- B: interleave k-pairs, swizzled dword scatter (LDS transpose)
        {
            uint32 d[8];
            d[0] = (a0.x & 0xffffu) | (a1.x << 16);
            d[1] = (a0.x >> 16)     | (a1.x & 0xffff0000u);
            d[2] = (a0.y & 0xffffu) | (a1.y << 16);
            d[3] = (a0.y >> 16)     | (a1.y & 0xffff0000u);
            d[4] = (a0.z & 0xffffu) | (a1.z << 16);
            d[5] = (a0.z >> 16)     | (a1.z & 0xffff0000u);
            d[6] = (a0.w & 0xffffu) | (a1.w << 16);
            d[7] = (a0.w >> 16)     | (a1.w & 0xffff0000u);
            uint32* lb = lB[bufc];
            #pragma unroll
            for (int j = 0; j < 8; ++j) lb[rowbase + j * 20 + kswz] = d[j];
        }
        __syncthreads();
        if (kb < 7) {
            wu0 = *(const uint4*)(wbRow + (kb + 1) * 32);
            wu1 = *(const uint4*)(wbRow + (kb + 1) * 32 + 8);
            const ushortt* xp = Xb + (size_t)((kb + 1) * 32 + 2 * kt) * HW + pq * 8;
            a0 = *(const uint4*)xp;
            a1 = *(const uint4*)(xp + HW);
        }
        short8 af[4], bf[4];
        const ushortt* lbU = (const ushortt*)lB[bufc];
        #pragma unroll
        for (int f = 0; f < 4; ++f) af[f] = *(const short8*)&lA[bufc][abase + f * 640];
        #pragma unroll
        for (int f = 0; f < 4; ++f) bf[f] = *(const short8*)&lbU[baddr[f]];
        #pragma unroll
        for (int fi = 0; fi < 4; ++fi)
            #pragma unroll
            for (int fj = 0; fj < 4; ++fj)
                acc[fi][fj] = __builtin_amdgcn_mfma_f32_16x16x32_bf16(
                    af[fi], bf[fj], acc[fi][fj], 0, 0, 0);
    }
    #pragma unroll
    for (int fi = 0; fi < 4; ++fi) {
        #pragma unroll
        for (int r = 0; r < 4; ++r) {
            int o_l = wm * 64 + fi * 16 + q4 * 4 + r;
            ushortt* dp = Dst + (size_t)o_l * HW + wn * 64 + l15;
            #pragma unroll
            for (int fj = 0; fj < 4; ++fj)
                dp[fj * 16] = f2bf(acc[fi][fj][r]);
        }
    }
}

// ---------- Stage D: 7x7 zero-padded conv, packed-fp32 dual-row FMA ----------
__global__ __launch_bounds__(256) void conv7(const ushortt* __restrict__ mixRe,
                                             const ushortt* __restrict__ mixIm,
                                             const float2* __restrict__ kern_pk,
                                             ushortt* __restrict__ outRe,
                                             ushortt* __restrict__ outIm) {
    __shared__ float tile[70 * 73];
    int b = blockIdx.z;
    int plane = blockIdx.y;
    int part = plane >> 8;
    size_t pbase = ((size_t)(b * 256 + (plane & 255))) << 14;
    const ushortt* src = (part ? mixIm : mixRe) + pbase;
    ushortt* dst = (part ? outIm : outRe) + pbase;
    int ty = (blockIdx.x >> 1) * 64, tx = (blockIdx.x & 1) * 64;
    int tid = threadIdx.x;
    const float2* kp = kern_pk + b * 56;

    for (int idx = tid; idx < 2520; idx += 256) {
        int row = idx / 36, du = idx - row * 36;
        int gy = ty + row - 3, gx0 = tx - 4 + 2 * du;
        uint32 v = 0u;
        if ((unsigned)gy < 128u && (unsigned)gx0 < 128u)
            v = *(const uint32*)(src + gy * 128 + gx0);
        int base = row * 73 + 2 * du;
        tile[base]     = __uint_as_float(v << 16);
        tile[base + 1] = __uint_as_float(v & 0xffff0000u);
    }
    __syncthreads();

    int ox = (tid & 7) * 8, oy = (tid >> 3) * 2;
    f32x2 acc2[8];
    #pragma unroll
    for (int j = 0; j < 8; ++j) { acc2[j].x = 0.f; acc2[j].y = 0.f; }

    #pragma unroll
    for (int dyy = 0; dyy < 8; ++dyy) {
        float row[14];
        #pragma unroll
        for (int m = 0; m < 14; ++m) row[m] = tile[(oy + dyy) * 73 + ox + 1 + m];
        #pragma unroll
        for (int dx = 0; dx < 7; ++dx) {
            float2 kl = kp[dyy * 7 + dx];
            f32x2 kk; kk.x = kl.x; kk.y = kl.y;
            #pragma unroll
            for (int j = 0; j < 8; ++j) {
                f32x2 rr; rr.x = row[dx + j]; rr.y = row[dx + j];
                acc2[j] = __builtin_elementwise_fma(rr, kk, acc2[j]);
            }
        }
    }

    uint32 s0[4], s1[4];
    #pragma unroll
    for (int m = 0; m < 4; ++m) {
        s0[m] = (uint32)f2bf(acc2[2 * m].x) | ((uint32)f2bf(acc2[2 * m + 1].x) << 16);
        s1[m] = (uint32)f2bf(acc2[2 * m].y) | ((uint32)f2bf(acc2[2 * m + 1].y) << 16);
    }
    *(uint4*)(dst + (ty + oy) * 128 + tx + ox)     = make_uint4(s0[0], s0[1], s0[2], s0[3]);
    *(uint4*)(dst + (ty + oy + 1) * 128 + tx + ox) = make_uint4(s1[0], s1[1], s1[2], s1[3]);
}

// ---------- Stage E: ifftshift + IFFT (conj trick, paired real-output cols) + x ----------
__global__ __launch_bounds__(1024) void ifft_add(const ushortt* __restrict__ convRe,
                                                 const ushortt* __restrict__ convIm,
                                                 const float* __restrict__ x,
                                                 float* __restrict__ out) {
    __shared__ float2 sc[128][129];
    __shared__ float twr[64], twi[64];
    int img = blockIdx.x;
    int tid = threadIdx.x, l = tid & 63, wv = tid >> 6;
    if (tid < 64) {
        float s, c;
        sincosf(-PIf * (float)tid / 64.0f, &s, &c);
        twr[tid] = c; twi[tid] = s;
    }
    const ushortt* cr = convRe + ((size_t)img << 14);
    const ushortt* ci = convIm + ((size_t)img << 14);
    const float* xi = x + (size_t)img * HW;
    __syncthreads();

    TwSet t = load_tw(twr, twi, l);
    bool u8 = (l & 8) != 0, u4 = (l & 4) != 0, u2 = (l & 2) != 0, u1 = (l & 1) != 0;
    int e = brev6(l);

    // ---- row pass: ifftshift gather (conj), ALL loads upfront, 8 FFTs
    {
        float nar[8], nai[8], nbr[8], nbi[8];
        #pragma unroll
        for (int r = 0; r < 8; ++r) {
            int p = ((wv * 8 + r) + 64) & 127;
            nar[r] = bf2f(cr[p * 128 + 64 + l]);
            nai[r] = bf2f(ci[p * 128 + 64 + l]);
            nbr[r] = bf2f(cr[p * 128 + l]);
            nbi[r] = bf2f(ci[p * 128 + l]);
        }
        #pragma unroll
        for (int r = 0; r < 8; ++r) {
            int u = wv * 8 + r;
            float Ar = nar[r], Ai = -nai[r], Br = nbr[r], Bi = -nbi[r];
            fft128_ps(Ar, Ai, Br, Bi, t, u8, u4, u2, u1);
            sc[u][e]      = make_float2(Ar, Ai);
            sc[u][e + 64] = make_float2(Br, Bi);
        }
    }
    __syncthreads();

    // ---- prefetch residual x (hidden under the col pass)
    float2 xv[8];
    #pragma unroll
    for (int k = 0; k < 8; ++k) {
        int idx2 = tid + k * 1024;
        xv[k] = *(const float2*)(xi + (idx2 >> 6) * 128 + (idx2 & 63) * 2);
    }

    // ---- col pass: 4 column-PAIR FFTs per wave, staged in regs
    float oar[4], oai[4], obr[4], obi[4];
    int rv  = (128 - l) & 127;       // reverse of row l
    int rv2 = (64 - l) & 127;        // reverse of row l+64
    #pragma unroll
    for (int r = 0; r < 4; ++r) {
        int m = wv * 4 + r;
        int c0 = 2 * m, c1 = 2 * m + 1;
        float2 P  = sc[l][c0],      R  = sc[l][c1];
        float2 Q  = sc[rv][c0],     S  = sc[rv][c1];
        float2 P2 = sc[l + 64][c0], R2 = sc[l + 64][c1];
        float2 Q2 = sc[rv2][c0],    S2 = sc[rv2][c1];
        float Ar = P.x + Q.x - R.y + S.y;
        float Ai = P.y - Q.y + R.x + S.x;
        float Br = P2.x + Q2.x - R2.y + S2.y;
        float Bi = P2.y - Q2.y + R2.x + S2.x;
        fft128_ps(Ar, Ai, Br, Bi, t, u8, u4, u2, u1);
        oar[r] = Ar; oai[r] = Ai; obr[r] = Br; obi[r] = Bi;
    }
    __syncthreads();
    #pragma unroll
    for (int r = 0; r < 4; ++r) {
        int m = wv * 4 + r;
        sc[e][m]      = make_float2(oar[r], oai[r]);   // (.x=col 2m, .y=col 2m+1)
        sc[e + 64][m] = make_float2(obr[r], obi[r]);
    }
    __syncthreads();

    // ---- output: slot m -> columns (2m, 2m+1); scale 1/256 (conj-trick 1/128 * pack 1/2)
    float* oo = out + (size_t)img * HW;
    #pragma unroll
    for (int k = 0; k < 8; ++k) {
        int idx2 = tid + k * 1024;
        int y = idx2 >> 6, m = idx2 & 63;
        float2 v = sc[y][m];
        float2 ov;
        ov.x = v.x * (1.0f / 256.0f) + xv[k].x;
        ov.y = v.y * (1.0f / 256.0f) + xv[k].y;
        *(float2*)(oo + y * 128 + 2 * m) = ov;
    }
}

extern "C" void kernel_launch(void* const* d_in, const int* in_sizes, int n_in,
                              void* d_out, int out_size, void* d_ws, size_t ws_size,
                              hipStream_t stream) {
    const float* x  = (const float*)d_in[0];
    const float* w1 = (const float*)d_in[1];
    const float* b1 = (const float*)d_in[2];
    const float* w2 = (const float*)d_in[3];
    const float* b2 = (const float*)d_in[4];
    const float* wr = (const float*)d_in[5];

    char* ws = (char*)d_ws;
    ushortt* xfRe  = (ushortt*)ws;                       // 64 MiB
    ushortt* xfIm  = xfRe + 33554432;                    // 64 MiB
    ushortt* mixRe = (ushortt*)(ws + 134217728);         // 64 MiB (separate: gemm in != out)
    ushortt* mixIm = mixRe + 33554432;                   // 64 MiB
    ushortt* convRe = xfRe, *convIm = xfIm;              // aliases (xf dead after gemm)
    float* magc = (float*)(ws + 268435456);
    float2* kern_pk = (float2*)(ws + 268435456 + 2048);  // 448 float2 = 3584 B
    ushortt* wbf = (ushortt*)(ws + 268435456 + 16384);   // 256x256 bf16 = 128 KiB

    hipMemsetAsync(magc, 0, 392 * sizeof(float), stream);
    fft_fwd<<<2048, 1024, 0, stream>>>(x, xfRe, xfIm, magc);
    mlp_kern<<<1, 256, 0, stream>>>(magc, w1, b1, w2, b2, wr, kern_pk, wbf);
    gemm_mix<<<dim3(128, 2, 16), 256, 0, stream>>>(xfRe, xfIm, wbf, mixRe, mixIm);
    conv7<<<dim3(4, 512, 8), 256, 0, stream>>>(mixRe, mixIm, kern_pk, convRe, convIm);
    ifft_add<<<2048, 1024, 0, stream>>>(convRe, convIm, x, (float*)d_out);
}